// Round 4
// baseline (292.596 us; speedup 1.0000x reference)
//
#include <hip/hip_runtime.h>
#include <hip/hip_bf16.h>
#include <stdint.h>

#define D_ 128
#define NB 64      // index rows per chunk
#define KCH 4      // chunks per gemm block
#define NINF (-__builtin_inff())

typedef float f32x4 __attribute__((ext_vector_type(4)));
typedef short bf16x8 __attribute__((ext_vector_type(8)));

__device__ inline unsigned short f2bf(float f){
  unsigned x = __float_as_uint(f);
  return (unsigned short)((x + 0x7FFFu + ((x >> 16) & 1u)) >> 16);  // RNE
}
__device__ inline unsigned packbf(float a, float b){
  return (unsigned)f2bf(a) | ((unsigned)f2bf(b) << 16);
}
// monotonic float->u32 key for atomicMax
__device__ inline unsigned fkey(float v){
  unsigned b = __float_as_uint(v);
  return (b & 0x80000000u) ? ~b : (b | 0x80000000u);
}

// ---- normalize queries f32 -> bf16 (one wave per row) ----
__global__ void k_norm_x(const float* __restrict__ x, unsigned short* __restrict__ xn){
  int row = blockIdx.x, lane = threadIdx.x;
  float2 v = reinterpret_cast<const float2*>(x + (size_t)row * D_)[lane];
  float ss = v.x * v.x + v.y * v.y;
  #pragma unroll
  for (int m = 1; m < 64; m <<= 1) ss += __shfl_xor(ss, m);
  float s = 1.0f / fmaxf(sqrtf(ss), 1e-12f);
  reinterpret_cast<unsigned*>(xn + (size_t)row * D_)[lane] = packbf(v.x * s, v.y * s);
}

// ---- class histogram ----
__global__ void k_hist(const int* __restrict__ lab, unsigned* __restrict__ hist, int N, int C){
  __shared__ unsigned lh[1024];
  int t = threadIdx.x;
  for (int c = t; c < 1024; c += 256) lh[c] = 0;
  __syncthreads();
  for (int i = blockIdx.x * 256 + t; i < N; i += gridDim.x * 256)
    atomicAdd(&lh[lab[i]], 1u);
  __syncthreads();
  for (int c = t; c < C; c += 256) { unsigned v = lh[c]; if (v) atomicAdd(&hist[c], v); }
}

// ---- exclusive scan -> per-class cursors (C <= 1024) ----
__global__ void k_scan(const unsigned* __restrict__ hist, unsigned* __restrict__ cursor, int C){
  __shared__ unsigned s[1024];
  int t = threadIdx.x;
  unsigned v = (t < C) ? hist[t] : 0u;
  s[t] = v; __syncthreads();
  for (int off = 1; off < 1024; off <<= 1){
    unsigned u = (t >= off) ? s[t - off] : 0u;
    __syncthreads();
    s[t] += u;
    __syncthreads();
  }
  if (t < C) cursor[t] = s[t] - v;
}

// ---- scatter: build class-sorted permutation + forward map ----
__global__ void k_scatter(const int* __restrict__ lab, unsigned* __restrict__ cursor,
                          int* __restrict__ perm, int* __restrict__ slab,
                          int* __restrict__ dstpos, int N){
  for (int i = blockIdx.x * 256 + threadIdx.x; i < N; i += gridDim.x * 256){
    int c = lab[i];
    unsigned pos = atomicAdd(&cursor[c], 1u);
    perm[pos] = i;
    slab[pos] = c;
    dstpos[i] = (int)pos;
  }
}

// ---- init output with key(-inf) ----
__global__ void k_init_out(unsigned* __restrict__ o, int n){
  int i = blockIdx.x * 256 + threadIdx.x;
  if (i < n) o[i] = 0x007FFFFFu;   // fkey(-inf)
}

// ---- stream-normalize + permute: seq f32 read -> bf16 scatter write ----
__global__ void k_permnorm(const float* __restrict__ emb, const int* __restrict__ dstpos,
                           unsigned short* __restrict__ nrm, int N){
  int r = blockIdx.x * 64 + (threadIdx.x >> 2);
  if (r >= N) return;
  int j = threadIdx.x & 3;
  const f32x4* src = reinterpret_cast<const f32x4*>(emb + (size_t)r * D_ + j * 32);
  f32x4 v[8];
  #pragma unroll
  for (int i = 0; i < 8; i++) v[i] = src[i];
  float ss = 0.f;
  #pragma unroll
  for (int i = 0; i < 8; i++) ss += v[i][0]*v[i][0] + v[i][1]*v[i][1] + v[i][2]*v[i][2] + v[i][3]*v[i][3];
  ss += __shfl_xor(ss, 1); ss += __shfl_xor(ss, 2);
  float sc = 1.0f / fmaxf(sqrtf(ss), 1e-12f);
  int d = dstpos[r];
  unsigned o[16];
  #pragma unroll
  for (int i = 0; i < 8; i++){
    o[i*2]   = packbf(v[i][0]*sc, v[i][1]*sc);
    o[i*2+1] = packbf(v[i][2]*sc, v[i][3]*sc);
  }
  uint4* dst = reinterpret_cast<uint4*>(nrm + (size_t)d * D_ + j * 32);
  #pragma unroll
  for (int i = 0; i < 4; i++) dst[i] = make_uint4(o[i*4], o[i*4+1], o[i*4+2], o[i*4+3]);
}

// ---- main GEMM + register segment-max; sequential staged bf16 reads ----
__global__ __launch_bounds__(256, 3) void k_gemm(
    const unsigned short* __restrict__ nrm,
    const unsigned short* __restrict__ xn,
    const int* __restrict__ slab,
    unsigned* __restrict__ out_u,
    int nchunks, int N, int C){
  __shared__ __align__(16) unsigned short Ab[2][NB * D_];
  const int t = threadIdx.x;
  const int w = t >> 6, lane = t & 63, lr = lane & 15, lg = lane >> 4;

  const int cbeg = blockIdx.x * KCH;
  if (cbeg >= nchunks) return;
  int cend = cbeg + KCH; if (cend > nchunks) cend = nchunks;

  // query fragments, live whole kernel (L2-resident source)
  bf16x8 bf[4][4];
  #pragma unroll
  for (int ni = 0; ni < 4; ni++)
    #pragma unroll
    for (int kk = 0; kk < 4; kk++)
      bf[ni][kk] = *reinterpret_cast<const bf16x8*>(
          xn + (size_t)(w * 64 + ni * 16 + lr) * D_ + kk * 32 + lg * 8);

  const int c0 = slab[(size_t)cbeg * NB];   // first class of this block (uniform)
  float rT0=NINF, rT1=NINF, rT2=NINF, rT3=NINF, rT4=NINF, rT5=NINF, rT6=NINF, rT7=NINF;

  auto stageF = [&](int cn, int bb){
    const char* sb = (const char*)(nrm + (size_t)cn * NB * D_);
    char* lb = (char*)(&Ab[bb][0]);
    #pragma unroll
    for (int i = 0; i < 4; i++){
      int L = t * 16 + i * 4096;            // linear LDS byte offset
      int row = L >> 8, s = (L >> 4) & 15;  // 16B slot within row
      int so = row * 256 + ((s ^ (row & 7)) << 4);  // inverse-swizzled global src
      __builtin_amdgcn_global_load_lds(
          (const __attribute__((address_space(1))) unsigned int*)(sb + so),
          (__attribute__((address_space(3))) unsigned int*)(lb + L),
          16, 0, 0);
    }
  };

  stageF(cbeg, 0);

  for (int c = cbeg; c < cend; ++c){
    const int b = (c - cbeg) & 1;
    const int rowbase = c * NB;
    // segment boundaries for this chunk (issue+consume BEFORE prefetch so the
    // implied vmcnt drain only hits already-landed loads)
    int rb = rowbase + lane;
    int myc = slab[rb < N ? rb : (N - 1)];
    int nx = __shfl_down(myc, 1);
    unsigned long long bmask = __ballot(lane < 63 && myc != nx);
    asm volatile("s_waitcnt vmcnt(0)" ::: "memory");   // chunk-c loads complete
    if (c + 1 < cend) stageF(c + 1, b ^ 1);            // prefetch rides over MFMA+epilogue
    asm volatile("s_barrier" ::: "memory");            // all waves: buf b ready

    f32x4 acc[4][4];
    #pragma unroll
    for (int mi = 0; mi < 4; mi++)
      #pragma unroll
      for (int ni = 0; ni < 4; ni++)
        acc[mi][ni] = (f32x4){0.f, 0.f, 0.f, 0.f};

    #pragma unroll
    for (int mi = 0; mi < 4; mi++){
      const int row = mi * 16 + lr;
      const char* rp = (const char*)(&Ab[b][0]) + row * 256;
      #pragma unroll
      for (int kk = 0; kk < 4; kk++){
        bf16x8 af = *reinterpret_cast<const bf16x8*>(rp + (((kk * 4 + lg) ^ (row & 7)) << 4));
        #pragma unroll
        for (int ni = 0; ni < 4; ni++)
          acc[mi][ni] = __builtin_amdgcn_mfma_f32_16x16x32_bf16(af, bf[ni][kk], acc[mi][ni], 0, 0, 0);
      }
    }

    // register epilogue: per-segment masked max, cross-lg reduce, slot update
    int a = 0;
    unsigned long long mm = bmask;
    for (;;){
      int e = mm ? (__builtin_ctzll(mm) + 1) : 64;
      int cls = __shfl(myc, a);
      float m0=NINF, m1=NINF, m2=NINF, m3=NINF;
      #pragma unroll
      for (int mi = 0; mi < 4; mi++)
        #pragma unroll
        for (int rg = 0; rg < 4; rg++){
          int row = mi * 16 + lg * 4 + rg;
          bool in = (row >= a) && (row < e) && (rowbase + row < N);
          m0 = in ? fmaxf(m0, acc[mi][0][rg]) : m0;
          m1 = in ? fmaxf(m1, acc[mi][1][rg]) : m1;
          m2 = in ? fmaxf(m2, acc[mi][2][rg]) : m2;
          m3 = in ? fmaxf(m3, acc[mi][3][rg]) : m3;
        }
      m0 = fmaxf(m0, __shfl_xor(m0, 16)); m0 = fmaxf(m0, __shfl_xor(m0, 32));
      m1 = fmaxf(m1, __shfl_xor(m1, 16)); m1 = fmaxf(m1, __shfl_xor(m1, 32));
      m2 = fmaxf(m2, __shfl_xor(m2, 16)); m2 = fmaxf(m2, __shfl_xor(m2, 32));
      m3 = fmaxf(m3, __shfl_xor(m3, 16)); m3 = fmaxf(m3, __shfl_xor(m3, 32));
      float mv = (lg < 2) ? ((lg == 0) ? m0 : m1) : ((lg == 2) ? m2 : m3);  // my q = t
      int slot = cls - c0;                 // uniform -> scalar branch
      switch (slot){
        case 0: rT0 = fmaxf(rT0, mv); break;
        case 1: rT1 = fmaxf(rT1, mv); break;
        case 2: rT2 = fmaxf(rT2, mv); break;
        case 3: rT3 = fmaxf(rT3, mv); break;
        case 4: rT4 = fmaxf(rT4, mv); break;
        case 5: rT5 = fmaxf(rT5, mv); break;
        case 6: rT6 = fmaxf(rT6, mv); break;
        case 7: rT7 = fmaxf(rT7, mv); break;
        default: atomicMax(&out_u[(size_t)t * C + cls], fkey(mv)); break;  // pathological span
      }
      if (e >= 64) break;
      a = e; mm &= mm - 1;
    }
    asm volatile("s_barrier" ::: "memory");            // all waves done reading buf b
  }

  // flush per-thread class maxima (thread t owns query q = t)
  const size_t ob = (size_t)t * C;
  #define FLUSH(S_, V_) { int cls = c0 + S_; if (cls < C && V_ != NINF) atomicMax(&out_u[ob + cls], fkey(V_)); }
  FLUSH(0, rT0) FLUSH(1, rT1) FLUSH(2, rT2) FLUSH(3, rT3)
  FLUSH(4, rT4) FLUSH(5, rT5) FLUSH(6, rT6) FLUSH(7, rT7)
  #undef FLUSH
}

// ================= fallback (round-1 path, if ws too small) =================
struct __align__(16) GSm {
  unsigned short A[NB * 136];
  float sims[16 * 257];
  float scale[NB];
  int rowid[NB];
  int clab[NB];
};

__global__ __launch_bounds__(256, 2) void k_gemm_gather(
    const float* __restrict__ emb, const unsigned short* __restrict__ xn,
    const int* __restrict__ perm, const int* __restrict__ slab,
    unsigned* __restrict__ out_u, int N, int C){
  __shared__ GSm sm;
  const int t = threadIdx.x;
  const int base = blockIdx.x * NB;
  if (t < NB){
    int p = base + t; if (p > N - 1) p = N - 1;
    sm.rowid[t] = perm[p];
    sm.clab[t]  = slab[p];
  }
  __syncthreads();
  {
    int r = t >> 2, j = t & 3;
    const float4* src = reinterpret_cast<const float4*>(emb + (long)sm.rowid[r] * D_ + j * 32);
    float4 v[8];
    #pragma unroll
    for (int i = 0; i < 8; i++) v[i] = src[i];
    float ss = 0.f;
    #pragma unroll
    for (int i = 0; i < 8; i++) ss += v[i].x*v[i].x + v[i].y*v[i].y + v[i].z*v[i].z + v[i].w*v[i].w;
    ss += __shfl_xor(ss, 1); ss += __shfl_xor(ss, 2);
    sm.scale[r] = 1.0f / fmaxf(sqrtf(ss), 1e-12f);
    unsigned* dst = reinterpret_cast<unsigned*>(&sm.A[r * 136 + j * 32]);
    #pragma unroll
    for (int i = 0; i < 8; i++){
      dst[i * 2]     = packbf(v[i].x, v[i].y);
      dst[i * 2 + 1] = packbf(v[i].z, v[i].w);
    }
  }
  const int w = t >> 6, lane = t & 63;
  const int lr = lane & 15, lg = lane >> 4;
  bf16x8 bfr[4][4];
  #pragma unroll
  for (int ni = 0; ni < 4; ni++)
    #pragma unroll
    for (int kk = 0; kk < 4; kk++)
      bfr[ni][kk] = *reinterpret_cast<const bf16x8*>(
          xn + (size_t)(w * 64 + ni * 16 + lr) * D_ + kk * 32 + lg * 8);
  f32x4 acc[4][4];
  #pragma unroll
  for (int mi = 0; mi < 4; mi++)
    #pragma unroll
    for (int ni = 0; ni < 4; ni++)
      acc[mi][ni] = (f32x4){0.f, 0.f, 0.f, 0.f};
  __syncthreads();
  #pragma unroll
  for (int mi = 0; mi < 4; mi++)
    #pragma unroll
    for (int kk = 0; kk < 4; kk++){
      bf16x8 af = *reinterpret_cast<const bf16x8*>(&sm.A[(mi * 16 + lr) * 136 + kk * 32 + lg * 8]);
      #pragma unroll
      for (int ni = 0; ni < 4; ni++)
        acc[mi][ni] = __builtin_amdgcn_mfma_f32_16x16x32_bf16(af, bfr[ni][kk], acc[mi][ni], 0, 0, 0);
    }
  int cur = -1; float rm = 0.f;
  for (int mi = 0; mi < 4; mi++){
    __syncthreads();
    #pragma unroll
    for (int ni = 0; ni < 4; ni++)
      #pragma unroll
      for (int rg = 0; rg < 4; rg++){
        int r16 = lg * 4 + rg;
        sm.sims[r16 * 257 + w * 64 + ni * 16 + lr] = acc[mi][ni][rg] * sm.scale[mi * 16 + r16];
      }
    __syncthreads();
    #pragma unroll
    for (int r16 = 0; r16 < 16; r16++){
      int c = sm.clab[mi * 16 + r16];
      float v = sm.sims[r16 * 257 + t];
      if (c != cur){
        if (cur >= 0) atomicMax(&out_u[(size_t)t * C + cur], fkey(rm));
        cur = c; rm = v;
      } else rm = fmaxf(rm, v);
    }
  }
  atomicMax(&out_u[(size_t)t * C + cur], fkey(rm));
}

// ---- unmap keys -> floats (in place) ----
__global__ void k_finalize(unsigned* __restrict__ o, int n){
  int i = blockIdx.x * 256 + threadIdx.x;
  if (i < n){
    unsigned k = o[i];
    o[i] = (k & 0x80000000u) ? (k & 0x7FFFFFFFu) : ~k;
  }
}

extern "C" void kernel_launch(void* const* d_in, const int* in_sizes, int n_in,
                              void* d_out, int out_size, void* d_ws, size_t ws_size,
                              hipStream_t stream){
  const float* x   = (const float*)d_in[0];
  const float* emb = (const float*)d_in[1];
  const int*   lab = (const int*)d_in[2];
  const int B = in_sizes[0] / D_;        // 256
  const int N = in_sizes[1] / D_;        // 200000
  const int C = out_size / B;            // 1000
  const int nchunks = (N + NB - 1) / NB; // 3125

  char* ws = (char*)d_ws;
  size_t off = 0;
  unsigned short* xn = (unsigned short*)(ws); off += ((size_t)B * D_ * 2 + 255) & ~(size_t)255;
  unsigned* hist   = (unsigned*)(ws + off); off += 4096;
  unsigned* cursor = (unsigned*)(ws + off); off += 4096;
  size_t narr = ((size_t)N * 4 + 255) & ~(size_t)255;
  int* perm   = (int*)(ws + off); off += narr;
  int* slab   = (int*)(ws + off); off += narr;
  int* dstpos = (int*)(ws + off); off += narr;
  unsigned short* nrm = (unsigned short*)(ws + off);
  size_t need = off + (size_t)nchunks * NB * D_ * 2;
  const bool fast = (ws_size >= need);

  k_norm_x<<<B, 64, 0, stream>>>(x, xn);
  hipMemsetAsync(hist, 0, 8192, stream);               // hist + cursor contiguous
  k_hist<<<208, 256, 0, stream>>>(lab, hist, N, C);
  k_scan<<<1, 1024, 0, stream>>>(hist, cursor, C);
  k_scatter<<<208, 256, 0, stream>>>(lab, cursor, perm, slab, dstpos, N);
  k_init_out<<<(B * C + 255) / 256, 256, 0, stream>>>((unsigned*)d_out, B * C);
  if (fast){
    k_permnorm<<<(N + 63) / 64, 256, 0, stream>>>(emb, dstpos, nrm, N);
    k_gemm<<<(nchunks + KCH - 1) / KCH, 256, 0, stream>>>(nrm, xn, slab, (unsigned*)d_out, nchunks, N, C);
  } else {
    k_gemm_gather<<<nchunks, 256, 0, stream>>>(emb, xn, perm, slab, (unsigned*)d_out, N, C);
  }
  k_finalize<<<(B * C + 255) / 256, 256, 0, stream>>>((unsigned*)d_out, B * C);
}

// Round 6
// 292.418 us; speedup vs baseline: 1.0006x; 1.0006x over previous
//
#include <hip/hip_runtime.h>
#include <hip/hip_bf16.h>
#include <stdint.h>

#define D_ 128
#define NB 64      // index rows per gemm block
#define NINF (-__builtin_inff())

typedef float f32x4 __attribute__((ext_vector_type(4)));
typedef short bf16x8 __attribute__((ext_vector_type(8)));

__device__ inline unsigned short f2bf(float f){
  unsigned x = __float_as_uint(f);
  return (unsigned short)((x + 0x7FFFu + ((x >> 16) & 1u)) >> 16);  // RNE
}
__device__ inline unsigned packbf(float a, float b){
  return (unsigned)f2bf(a) | ((unsigned)f2bf(b) << 16);
}
// monotonic float->u32 key for atomicMax
__device__ inline unsigned fkey(float v){
  unsigned b = __float_as_uint(v);
  return (b & 0x80000000u) ? ~b : (b | 0x80000000u);
}

// ---- fused prep: {normalize emb -> nrmlin (linear)}, {normalize x -> xn},
// ----             {init out keys}, {class histogram}; role by blockIdx ----
__global__ void k_prep(const float* __restrict__ emb, const float* __restrict__ x,
                       unsigned short* __restrict__ nrmlin, unsigned short* __restrict__ xn,
                       unsigned* __restrict__ out_u, const int* __restrict__ lab,
                       unsigned* __restrict__ hist,
                       int N, int B, int C, int PN, int XB, int IB, int HB){
  const int bid = blockIdx.x;
  const int t = threadIdx.x;
  if (bid < PN + XB){
    const float* src; unsigned short* dst; int nrows; int r0;
    if (bid < PN){ src = emb; dst = nrmlin; nrows = N; r0 = bid * 64; }
    else         { src = x;   dst = xn;     nrows = B; r0 = (bid - PN) * 64; }
    int r = r0 + (t >> 2);
    if (r >= nrows) return;
    int j = t & 3;
    const f32x4* s4 = reinterpret_cast<const f32x4*>(src + (size_t)r * D_ + j * 32);
    f32x4 v[8];
    #pragma unroll
    for (int i = 0; i < 8; i++) v[i] = s4[i];
    float ss = 0.f;
    #pragma unroll
    for (int i = 0; i < 8; i++) ss += v[i][0]*v[i][0] + v[i][1]*v[i][1] + v[i][2]*v[i][2] + v[i][3]*v[i][3];
    ss += __shfl_xor(ss, 1); ss += __shfl_xor(ss, 2);
    float sc = 1.0f / fmaxf(sqrtf(ss), 1e-12f);
    unsigned o[16];
    #pragma unroll
    for (int i = 0; i < 8; i++){
      o[i*2]   = packbf(v[i][0]*sc, v[i][1]*sc);
      o[i*2+1] = packbf(v[i][2]*sc, v[i][3]*sc);
    }
    uint4* d4 = reinterpret_cast<uint4*>(dst + (size_t)r * D_ + j * 32);
    #pragma unroll
    for (int i = 0; i < 4; i++) d4[i] = make_uint4(o[i*4], o[i*4+1], o[i*4+2], o[i*4+3]);
  } else if (bid < PN + XB + IB){
    int i = (bid - PN - XB) * 256 + t;
    if (i < B * C) out_u[i] = 0x007FFFFFu;   // fkey(-inf)
  } else {
    int hb = bid - PN - XB - IB;
    __shared__ unsigned lh[1024];
    for (int c = t; c < 1024; c += 256) lh[c] = 0;
    __syncthreads();
    for (int i = hb * 256 + t; i < N; i += HB * 256) atomicAdd(&lh[lab[i]], 1u);
    __syncthreads();
    for (int c = t; c < C; c += 256){ unsigned v = lh[c]; if (v) atomicAdd(&hist[c], v); }
  }
}

// ---- exclusive scan -> per-class cursors (C <= 1024) ----
__global__ void k_scan(const unsigned* __restrict__ hist, unsigned* __restrict__ cursor, int C){
  __shared__ unsigned s[1024];
  int t = threadIdx.x;
  unsigned v = (t < C) ? hist[t] : 0u;
  s[t] = v; __syncthreads();
  for (int off = 1; off < 1024; off <<= 1){
    unsigned u = (t >= off) ? s[t - off] : 0u;
    __syncthreads();
    s[t] += u;
    __syncthreads();
  }
  if (t < C) cursor[t] = s[t] - v;
}

// ---- scatter: build class-sorted permutation ----
__global__ void k_scatter(const int* __restrict__ lab, unsigned* __restrict__ cursor,
                          int* __restrict__ perm, int* __restrict__ slab, int N){
  for (int i = blockIdx.x * 256 + threadIdx.x; i < N; i += gridDim.x * 256){
    int c = lab[i];
    unsigned pos = atomicAdd(&cursor[c], 1u);
    perm[pos] = i;
    slab[pos] = c;
  }
}

// ---- main GEMM + register segment-max; one chunk per block, gather staging ----
__global__ __launch_bounds__(256, 3) void k_gemm(
    const unsigned short* __restrict__ nrmlin,
    const unsigned short* __restrict__ xn,
    const int* __restrict__ perm, const int* __restrict__ slab,
    unsigned* __restrict__ out_u, int N, int C){
  __shared__ __align__(16) unsigned short Ab[NB * D_];   // 16 KB, fragment-major
  const int t = threadIdx.x, w = t >> 6, lane = t & 63, lr = lane & 15, lg = lane >> 4;
  const int rowbase = blockIdx.x * NB;

  // per-lane class labels (identical across waves) — issue early, consumed late
  int rb = rowbase + lane;
  int myc = slab[rb < N ? rb : (N - 1)];

  // gather-stage into fragment-major LDS: wave w stages kk=w, i-th load stages mi=i.
  // LDS dest = f*1024 + lane*16 (wave-uniform base + lane*16 — legal for global_load_lds);
  // global src = perm-row * 256B + slot*16B, slot = kk*4+lg. Clamped rows duplicate
  // row N-1 (same class as last row -> max unchanged).
  #pragma unroll
  for (int i = 0; i < 4; i++){
    int gr = rowbase + i * 16 + lr; if (gr > N - 1) gr = N - 1;
    int g = perm[gr];                               // 16 lanes share value (L2/L3)
    const char* src = (const char*)nrmlin + (size_t)g * 256 + ((w * 4 + lg) << 4);
    char* dst = (char*)Ab + (w + i * 4) * 1024 + lane * 16;
    __builtin_amdgcn_global_load_lds(
        (const __attribute__((address_space(1))) unsigned int*)src,
        (__attribute__((address_space(3))) unsigned int*)dst, 16, 0, 0);
  }

  // query fragments from xn (L2-resident): wave w covers queries [w*64, w*64+64)
  bf16x8 bf[4][4];
  #pragma unroll
  for (int ni = 0; ni < 4; ni++)
    #pragma unroll
    for (int kk = 0; kk < 4; kk++)
      bf[ni][kk] = *reinterpret_cast<const bf16x8*>(
          xn + (size_t)(w * 64 + ni * 16 + lr) * D_ + kk * 32 + lg * 8);

  // segment boundaries
  int nx = __shfl_down(myc, 1);
  unsigned long long bmask = __ballot(lane < 63 && myc != nx);
  int c0 = __shfl(myc, 0);

  __syncthreads();   // drains vmcnt (gll + perm + slab + bf) and barriers: Ab ready

  f32x4 acc[4][4];
  #pragma unroll
  for (int mi = 0; mi < 4; mi++)
    #pragma unroll
    for (int ni = 0; ni < 4; ni++)
      acc[mi][ni] = (f32x4){0.f, 0.f, 0.f, 0.f};

  // canonical conflict-free ds_read_b128: offset = f*512 + lane*8 (ushorts)
  #pragma unroll
  for (int mi = 0; mi < 4; mi++)
    #pragma unroll
    for (int kk = 0; kk < 4; kk++){
      bf16x8 af = *reinterpret_cast<const bf16x8*>(&Ab[(mi * 4 + kk) * 512 + lane * 8]);
      #pragma unroll
      for (int ni = 0; ni < 4; ni++)
        acc[mi][ni] = __builtin_amdgcn_mfma_f32_16x16x32_bf16(af, bf[ni][kk], acc[mi][ni], 0, 0, 0);
    }

  // epilogue: thread t owns query t (mv selected by ni=lg after cross-lg reduce)
  if (bmask == 0ULL){
    // fast path: whole chunk is one class
    float m0=NINF, m1=NINF, m2=NINF, m3=NINF;
    #pragma unroll
    for (int mi = 0; mi < 4; mi++)
      #pragma unroll
      for (int rg = 0; rg < 4; rg++){
        m0 = fmaxf(m0, acc[mi][0][rg]);
        m1 = fmaxf(m1, acc[mi][1][rg]);
        m2 = fmaxf(m2, acc[mi][2][rg]);
        m3 = fmaxf(m3, acc[mi][3][rg]);
      }
    m0 = fmaxf(m0, __shfl_xor(m0, 16)); m0 = fmaxf(m0, __shfl_xor(m0, 32));
    m1 = fmaxf(m1, __shfl_xor(m1, 16)); m1 = fmaxf(m1, __shfl_xor(m1, 32));
    m2 = fmaxf(m2, __shfl_xor(m2, 16)); m2 = fmaxf(m2, __shfl_xor(m2, 32));
    m3 = fmaxf(m3, __shfl_xor(m3, 16)); m3 = fmaxf(m3, __shfl_xor(m3, 32));
    float mv = (lg < 2) ? ((lg == 0) ? m0 : m1) : ((lg == 2) ? m2 : m3);
    atomicMax(&out_u[(size_t)t * C + c0], fkey(mv));
  } else {
    int a = 0;
    unsigned long long mm = bmask;
    for (;;){
      int e = mm ? (__builtin_ctzll(mm) + 1) : 64;
      int cls = __shfl(myc, a);
      float m0=NINF, m1=NINF, m2=NINF, m3=NINF;
      #pragma unroll
      for (int mi = 0; mi < 4; mi++)
        #pragma unroll
        for (int rg = 0; rg < 4; rg++){
          int row = mi * 16 + lg * 4 + rg;
          bool in = (row >= a) && (row < e);
          m0 = in ? fmaxf(m0, acc[mi][0][rg]) : m0;
          m1 = in ? fmaxf(m1, acc[mi][1][rg]) : m1;
          m2 = in ? fmaxf(m2, acc[mi][2][rg]) : m2;
          m3 = in ? fmaxf(m3, acc[mi][3][rg]) : m3;
        }
      m0 = fmaxf(m0, __shfl_xor(m0, 16)); m0 = fmaxf(m0, __shfl_xor(m0, 32));
      m1 = fmaxf(m1, __shfl_xor(m1, 16)); m1 = fmaxf(m1, __shfl_xor(m1, 32));
      m2 = fmaxf(m2, __shfl_xor(m2, 16)); m2 = fmaxf(m2, __shfl_xor(m2, 32));
      m3 = fmaxf(m3, __shfl_xor(m3, 16)); m3 = fmaxf(m3, __shfl_xor(m3, 32));
      float mv = (lg < 2) ? ((lg == 0) ? m0 : m1) : ((lg == 2) ? m2 : m3);
      atomicMax(&out_u[(size_t)t * C + cls], fkey(mv));
      if (e >= 64) break;
      a = e; mm &= mm - 1;
    }
  }
}

// ================= fallback (round-1 path, if ws too small) =================
struct __align__(16) GSm {
  unsigned short A[NB * 136];
  float sims[16 * 257];
  float scale[NB];
  int rowid[NB];
  int clab[NB];
};

__global__ __launch_bounds__(256, 2) void k_gemm_gather(
    const float* __restrict__ emb, const unsigned short* __restrict__ xn,
    const int* __restrict__ perm, const int* __restrict__ slab,
    unsigned* __restrict__ out_u, int N, int C){
  __shared__ GSm sm;
  const int t = threadIdx.x;
  const int base = blockIdx.x * NB;
  if (t < NB){
    int p = base + t; if (p > N - 1) p = N - 1;
    sm.rowid[t] = perm[p];
    sm.clab[t]  = slab[p];
  }
  __syncthreads();
  {
    int r = t >> 2, j = t & 3;
    const float4* src = reinterpret_cast<const float4*>(emb + (long)sm.rowid[r] * D_ + j * 32);
    float4 v[8];
    #pragma unroll
    for (int i = 0; i < 8; i++) v[i] = src[i];
    float ss = 0.f;
    #pragma unroll
    for (int i = 0; i < 8; i++) ss += v[i].x*v[i].x + v[i].y*v[i].y + v[i].z*v[i].z + v[i].w*v[i].w;
    ss += __shfl_xor(ss, 1); ss += __shfl_xor(ss, 2);
    sm.scale[r] = 1.0f / fmaxf(sqrtf(ss), 1e-12f);
    unsigned* dst = reinterpret_cast<unsigned*>(&sm.A[r * 136 + j * 32]);
    #pragma unroll
    for (int i = 0; i < 8; i++){
      dst[i * 2]     = packbf(v[i].x, v[i].y);
      dst[i * 2 + 1] = packbf(v[i].z, v[i].w);
    }
  }
  const int w = t >> 6, lane = t & 63;
  const int lr = lane & 15, lg = lane >> 4;
  bf16x8 bfr[4][4];
  #pragma unroll
  for (int ni = 0; ni < 4; ni++)
    #pragma unroll
    for (int kk = 0; kk < 4; kk++)
      bfr[ni][kk] = *reinterpret_cast<const bf16x8*>(
          xn + (size_t)(w * 64 + ni * 16 + lr) * D_ + kk * 32 + lg * 8);
  f32x4 acc[4][4];
  #pragma unroll
  for (int mi = 0; mi < 4; mi++)
    #pragma unroll
    for (int ni = 0; ni < 4; ni++)
      acc[mi][ni] = (f32x4){0.f, 0.f, 0.f, 0.f};
  __syncthreads();
  #pragma unroll
  for (int mi = 0; mi < 4; mi++)
    #pragma unroll
    for (int kk = 0; kk < 4; kk++){
      bf16x8 af = *reinterpret_cast<const bf16x8*>(&sm.A[(mi * 16 + lr) * 136 + kk * 32 + lg * 8]);
      #pragma unroll
      for (int ni = 0; ni < 4; ni++)
        acc[mi][ni] = __builtin_amdgcn_mfma_f32_16x16x32_bf16(af, bfr[ni][kk], acc[mi][ni], 0, 0, 0);
    }
  int cur = -1; float rm = 0.f;
  for (int mi = 0; mi < 4; mi++){
    __syncthreads();
    #pragma unroll
    for (int ni = 0; ni < 4; ni++)
      #pragma unroll
      for (int rg = 0; rg < 4; rg++){
        int r16 = lg * 4 + rg;
        sm.sims[r16 * 257 + w * 64 + ni * 16 + lr] = acc[mi][ni][rg] * sm.scale[mi * 16 + r16];
      }
    __syncthreads();
    #pragma unroll
    for (int r16 = 0; r16 < 16; r16++){
      int c = sm.clab[mi * 16 + r16];
      float v = sm.sims[r16 * 257 + t];
      if (c != cur){
        if (cur >= 0) atomicMax(&out_u[(size_t)t * C + cur], fkey(rm));
        cur = c; rm = v;
      } else rm = fmaxf(rm, v);
    }
  }
  atomicMax(&out_u[(size_t)t * C + cur], fkey(rm));
}

// ---- unmap keys -> floats (in place) ----
__global__ void k_finalize(unsigned* __restrict__ o, int n){
  int i = blockIdx.x * 256 + threadIdx.x;
  if (i < n){
    unsigned k = o[i];
    o[i] = (k & 0x80000000u) ? (k & 0x7FFFFFFFu) : ~k;
  }
}

extern "C" void kernel_launch(void* const* d_in, const int* in_sizes, int n_in,
                              void* d_out, int out_size, void* d_ws, size_t ws_size,
                              hipStream_t stream){
  const float* x   = (const float*)d_in[0];
  const float* emb = (const float*)d_in[1];
  const int*   lab = (const int*)d_in[2];
  const int B = in_sizes[0] / D_;        // 256
  const int N = in_sizes[1] / D_;        // 200000
  const int C = out_size / B;            // 1000

  const int PNfull = (N + 63) / 64;      // 3125
  const int XB = (B + 63) / 64;          // 4
  const int IB = (B * C + 255) / 256;    // 1000
  const int HB = 208;

  char* ws = (char*)d_ws;
  size_t off = 0;
  unsigned short* xn = (unsigned short*)(ws); off += ((size_t)B * D_ * 2 + 255) & ~(size_t)255;
  unsigned* hist   = (unsigned*)(ws + off); off += 4096;
  unsigned* cursor = (unsigned*)(ws + off); off += 4096;
  size_t narr = ((size_t)N * 4 + 255) & ~(size_t)255;
  int* perm   = (int*)(ws + off); off += narr;
  int* slab   = (int*)(ws + off); off += narr;
  unsigned short* nrmlin = (unsigned short*)(ws + off);
  size_t need = off + (size_t)PNfull * NB * D_ * 2;
  const bool fast = (ws_size >= need);
  const int PN = fast ? PNfull : 0;      // skip permnorm role if ws too small

  hipMemsetAsync(hist, 0, 4096, stream);
  k_prep<<<PN + XB + IB + HB, 256, 0, stream>>>(emb, x, nrmlin, xn, (unsigned*)d_out,
                                                lab, hist, N, B, C, PN, XB, IB, HB);
  k_scan<<<1, 1024, 0, stream>>>(hist, cursor, C);
  k_scatter<<<208, 256, 0, stream>>>(lab, cursor, perm, slab, N);
  if (fast){
    k_gemm<<<PNfull, 256, 0, stream>>>(nrmlin, xn, perm, slab, (unsigned*)d_out, N, C);
  } else {
    k_gemm_gather<<<PNfull, 256, 0, stream>>>(emb, xn, perm, slab, (unsigned*)d_out, N, C);
  }
  k_finalize<<<IB, 256, 0, stream>>>((unsigned*)d_out, B * C);
}

// Round 12
// 243.116 us; speedup vs baseline: 1.2035x; 1.2028x over previous
//
#include <hip/hip_runtime.h>
#include <hip/hip_bf16.h>
#include <stdint.h>

#define D_ 128
#define NB 64      // index rows per chunk
#define NINF (-__builtin_inff())

typedef float f32x4 __attribute__((ext_vector_type(4)));
typedef short bf16x8 __attribute__((ext_vector_type(8)));

__device__ inline unsigned short f2bf(float f){
  unsigned x = __float_as_uint(f);
  return (unsigned short)((x + 0x7FFFu + ((x >> 16) & 1u)) >> 16);  // RNE
}
__device__ inline unsigned packbf(float a, float b){
  return (unsigned)f2bf(a) | ((unsigned)f2bf(b) << 16);
}
// monotonic float->u32 key for atomicMax (fallback path only)
__device__ inline unsigned fkey(float v){
  unsigned b = __float_as_uint(v);
  return (b & 0x80000000u) ? ~b : (b | 0x80000000u);
}

// ---- fused prep: {normalize emb -> nrmlin (linear bf16)}, {normalize x -> xn},
// ----             {class histogram}; role by blockIdx ----
__global__ void k_prep(const float* __restrict__ emb, const float* __restrict__ x,
                       unsigned short* __restrict__ nrmlin, unsigned short* __restrict__ xn,
                       const int* __restrict__ lab, unsigned* __restrict__ hist,
                       int N, int B, int C, int PN, int XB, int HB){
  const int bid = blockIdx.x;
  const int t = threadIdx.x;
  if (bid < PN + XB){
    const float* src; unsigned short* dst; int nrows; int r0;
    if (bid < PN){ src = emb; dst = nrmlin; nrows = N; r0 = bid * 64; }
    else         { src = x;   dst = xn;     nrows = B; r0 = (bid - PN) * 64; }
    int r = r0 + (t >> 2);
    if (r >= nrows) return;
    int j = t & 3;
    const f32x4* s4 = reinterpret_cast<const f32x4*>(src + (size_t)r * D_ + j * 32);
    f32x4 v[8];
    #pragma unroll
    for (int i = 0; i < 8; i++) v[i] = s4[i];
    float ss = 0.f;
    #pragma unroll
    for (int i = 0; i < 8; i++) ss += v[i][0]*v[i][0] + v[i][1]*v[i][1] + v[i][2]*v[i][2] + v[i][3]*v[i][3];
    ss += __shfl_xor(ss, 1); ss += __shfl_xor(ss, 2);
    float sc = 1.0f / fmaxf(sqrtf(ss), 1e-12f);
    unsigned o[16];
    #pragma unroll
    for (int i = 0; i < 8; i++){
      o[i*2]   = packbf(v[i][0]*sc, v[i][1]*sc);
      o[i*2+1] = packbf(v[i][2]*sc, v[i][3]*sc);
    }
    uint4* d4 = reinterpret_cast<uint4*>(dst + (size_t)r * D_ + j * 32);
    #pragma unroll
    for (int i = 0; i < 4; i++) d4[i] = make_uint4(o[i*4], o[i*4+1], o[i*4+2], o[i*4+3]);
  } else {
    int hb = bid - PN - XB;
    __shared__ unsigned lh[1024];
    for (int c = t; c < 1024; c += 256) lh[c] = 0;
    __syncthreads();
    for (int i = hb * 256 + t; i < N; i += HB * 256) atomicAdd(&lh[lab[i]], 1u);
    __syncthreads();
    for (int c = t; c < C; c += 256){ unsigned v = lh[c]; if (v) atomicAdd(&hist[c], v); }
  }
}

// ---- exclusive scan -> cursors (mutable) + cbase (immutable), C <= 1024 ----
__global__ void k_scan(const unsigned* __restrict__ hist, unsigned* __restrict__ cursor,
                       unsigned* __restrict__ cbase, int C){
  __shared__ unsigned s[1024];
  int t = threadIdx.x;
  unsigned v = (t < C) ? hist[t] : 0u;
  s[t] = v; __syncthreads();
  for (int off = 1; off < 1024; off <<= 1){
    unsigned u = (t >= off) ? s[t - off] : 0u;
    __syncthreads();
    s[t] += u;
    __syncthreads();
  }
  if (t < C){ unsigned e = s[t] - v; cursor[t] = e; cbase[t] = e; }
}

// ---- scatter: build class-sorted permutation (slab only for fallback) ----
__global__ void k_scatter(const int* __restrict__ lab, unsigned* __restrict__ cursor,
                          int* __restrict__ perm, int* __restrict__ slab, int N){
  for (int i = blockIdx.x * 256 + threadIdx.x; i < N; i += gridDim.x * 256){
    int c = lab[i];
    unsigned pos = atomicAdd(&cursor[c], 1u);
    perm[pos] = i;
    slab[pos] = c;
  }
}

// ---- main: one block per class; loop chunks; register max; ZERO atomics ----
__global__ __launch_bounds__(256, 2) void k_gemm_cls(
    const unsigned short* __restrict__ nrmlin,
    const unsigned short* __restrict__ xn,
    const int* __restrict__ perm,
    const unsigned* __restrict__ cbase, const unsigned* __restrict__ hist,
    float* __restrict__ out, int N, int C){
  const int c = blockIdx.x;
  const int t = threadIdx.x, w = t >> 6, lane = t & 63, lr = lane & 15, lg = lane >> 4;
  const int nrows = (int)hist[c];
  if (nrows == 0){ out[(size_t)t * C + c] = NINF; return; }
  const int base = (int)cbase[c];
  const int last = base + nrows - 1;
  const int chunks = (nrows + NB - 1) >> 6;

  __shared__ __align__(16) unsigned short Ab[2][NB * D_];   // 2 x 16 KB, fragment-major

  // helper lambdas ---------------------------------------------------------
  auto rid_load = [&](int ci, int (&r)[4]){
    int cc = ci < chunks ? ci : chunks - 1;          // clamped (harmless re-gather)
    #pragma unroll
    for (int i = 0; i < 4; i++){
      int gr = base + cc * NB + i * 16 + lr;
      if (gr > last) gr = last;                      // duplicate same-class row
      r[i] = perm[gr];
    }
  };
  auto stage = [&](int bb, const int (&r)[4]){
    #pragma unroll
    for (int i = 0; i < 4; i++){
      const char* src = (const char*)nrmlin + (size_t)r[i] * 256 + ((w * 4 + lg) << 4);
      char* dst = (char*)(&Ab[bb][0]) + (w + i * 4) * 1024 + lane * 16;
      __builtin_amdgcn_global_load_lds(
          (const __attribute__((address_space(1))) unsigned int*)src,
          (__attribute__((address_space(3))) unsigned int*)dst, 16, 0, 0);
    }
  };

  // prologue: stage chunk 0, prefetch rids for chunk 1
  int ridN[4];
  rid_load(0, ridN);
  stage(0, ridN);
  rid_load(1, ridN);

  // query fragments (xn is L2/L3-hot, 64 KB total)
  bf16x8 bf[4][4];
  #pragma unroll
  for (int ni = 0; ni < 4; ni++)
    #pragma unroll
    for (int kk = 0; kk < 4; kk++)
      bf[ni][kk] = *reinterpret_cast<const bf16x8*>(
          xn + (size_t)(w * 64 + ni * 16 + lr) * D_ + kk * 32 + lg * 8);

  float M0 = NINF, M1 = NINF, M2 = NINF, M3 = NINF;

  for (int ci = 0; ci < chunks; ++ci){
    const int b = ci & 1;
    // consuming ridN forces (in-order vmcnt) own gll(ci) drained; then overlap:
    stage(b ^ 1, ridN);            // prefetch chunk ci+1 (clamped on tail)
    rid_load(ci + 2, ridN);        // prefetch rids for chunk ci+2
    __builtin_amdgcn_s_barrier();  // all waves: Ab[b] fully staged

    f32x4 acc[4][4];
    #pragma unroll
    for (int mi = 0; mi < 4; mi++)
      #pragma unroll
      for (int ni = 0; ni < 4; ni++)
        acc[mi][ni] = (f32x4){0.f, 0.f, 0.f, 0.f};

    #pragma unroll
    for (int mi = 0; mi < 4; mi++)
      #pragma unroll
      for (int kk = 0; kk < 4; kk++){
        bf16x8 af = *reinterpret_cast<const bf16x8*>(&Ab[b][(mi * 4 + kk) * 512 + lane * 8]);
        #pragma unroll
        for (int ni = 0; ni < 4; ni++)
          acc[mi][ni] = __builtin_amdgcn_mfma_f32_16x16x32_bf16(af, bf[ni][kk], acc[mi][ni], 0, 0, 0);
      }
    __builtin_amdgcn_s_barrier();  // all waves done reading Ab[b] (next iter overwrites it)

    // register epilogue: no masks needed — tail rows are same-class duplicates
    #pragma unroll
    for (int mi = 0; mi < 4; mi++)
      #pragma unroll
      for (int rg = 0; rg < 4; rg++){
        M0 = fmaxf(M0, acc[mi][0][rg]);
        M1 = fmaxf(M1, acc[mi][1][rg]);
        M2 = fmaxf(M2, acc[mi][2][rg]);
        M3 = fmaxf(M3, acc[mi][3][rg]);
      }
  }
  asm volatile("s_waitcnt vmcnt(0)" ::: "memory");   // drain trailing prefetch before endpgm

  // cross-lg reduce (lanes differ in lg = bits 4..5), select own query = t
  M0 = fmaxf(M0, __shfl_xor(M0, 16)); M0 = fmaxf(M0, __shfl_xor(M0, 32));
  M1 = fmaxf(M1, __shfl_xor(M1, 16)); M1 = fmaxf(M1, __shfl_xor(M1, 32));
  M2 = fmaxf(M2, __shfl_xor(M2, 16)); M2 = fmaxf(M2, __shfl_xor(M2, 32));
  M3 = fmaxf(M3, __shfl_xor(M3, 16)); M3 = fmaxf(M3, __shfl_xor(M3, 32));
  float mv = (lg < 2) ? ((lg == 0) ? M0 : M1) : ((lg == 2) ? M2 : M3);
  out[(size_t)t * C + c] = mv;     // exactly one plain store per (query, class)
}

// ================= fallback (if ws too small): round-1 path =================
__global__ void k_init_out(unsigned* __restrict__ o, int n){
  int i = blockIdx.x * 256 + threadIdx.x;
  if (i < n) o[i] = 0x007FFFFFu;   // fkey(-inf)
}

struct __align__(16) GSm {
  unsigned short A[NB * 136];
  float sims[16 * 257];
  float scale[NB];
  int rowid[NB];
  int clab[NB];
};

__global__ __launch_bounds__(256, 2) void k_gemm_gather(
    const float* __restrict__ emb, const unsigned short* __restrict__ xn,
    const int* __restrict__ perm, const int* __restrict__ slab,
    unsigned* __restrict__ out_u, int N, int C){
  __shared__ GSm sm;
  const int t = threadIdx.x;
  const int base = blockIdx.x * NB;
  if (t < NB){
    int p = base + t; if (p > N - 1) p = N - 1;
    sm.rowid[t] = perm[p];
    sm.clab[t]  = slab[p];
  }
  __syncthreads();
  {
    int r = t >> 2, j = t & 3;
    const float4* src = reinterpret_cast<const float4*>(emb + (long)sm.rowid[r] * D_ + j * 32);
    float4 v[8];
    #pragma unroll
    for (int i = 0; i < 8; i++) v[i] = src[i];
    float ss = 0.f;
    #pragma unroll
    for (int i = 0; i < 8; i++) ss += v[i].x*v[i].x + v[i].y*v[i].y + v[i].z*v[i].z + v[i].w*v[i].w;
    ss += __shfl_xor(ss, 1); ss += __shfl_xor(ss, 2);
    sm.scale[r] = 1.0f / fmaxf(sqrtf(ss), 1e-12f);
    unsigned* dst = reinterpret_cast<unsigned*>(&sm.A[r * 136 + j * 32]);
    #pragma unroll
    for (int i = 0; i < 8; i++){
      dst[i * 2]     = packbf(v[i].x, v[i].y);
      dst[i * 2 + 1] = packbf(v[i].z, v[i].w);
    }
  }
  const int w = t >> 6, lane = t & 63;
  const int lr = lane & 15, lg = lane >> 4;
  bf16x8 bfr[4][4];
  #pragma unroll
  for (int ni = 0; ni < 4; ni++)
    #pragma unroll
    for (int kk = 0; kk < 4; kk++)
      bfr[ni][kk] = *reinterpret_cast<const bf16x8*>(
          xn + (size_t)(w * 64 + ni * 16 + lr) * D_ + kk * 32 + lg * 8);
  f32x4 acc[4][4];
  #pragma unroll
  for (int mi = 0; mi < 4; mi++)
    #pragma unroll
    for (int ni = 0; ni < 4; ni++)
      acc[mi][ni] = (f32x4){0.f, 0.f, 0.f, 0.f};
  __syncthreads();
  #pragma unroll
  for (int mi = 0; mi < 4; mi++)
    #pragma unroll
    for (int kk = 0; kk < 4; kk++){
      bf16x8 af = *reinterpret_cast<const bf16x8*>(&sm.A[(mi * 16 + lr) * 136 + kk * 32 + lg * 8]);
      #pragma unroll
      for (int ni = 0; ni < 4; ni++)
        acc[mi][ni] = __builtin_amdgcn_mfma_f32_16x16x32_bf16(af, bfr[ni][kk], acc[mi][ni], 0, 0, 0);
    }
  int cur = -1; float rm = 0.f;
  for (int mi = 0; mi < 4; mi++){
    __syncthreads();
    #pragma unroll
    for (int ni = 0; ni < 4; ni++)
      #pragma unroll
      for (int rg = 0; rg < 4; rg++){
        int r16 = lg * 4 + rg;
        sm.sims[r16 * 257 + w * 64 + ni * 16 + lr] = acc[mi][ni][rg] * sm.scale[mi * 16 + r16];
      }
    __syncthreads();
    #pragma unroll
    for (int r16 = 0; r16 < 16; r16++){
      int cc = sm.clab[mi * 16 + r16];
      float v = sm.sims[r16 * 257 + t];
      if (cc != cur){
        if (cur >= 0) atomicMax(&out_u[(size_t)t * C + cur], fkey(rm));
        cur = cc; rm = v;
      } else rm = fmaxf(rm, v);
    }
  }
  atomicMax(&out_u[(size_t)t * C + cur], fkey(rm));
}

__global__ void k_finalize(unsigned* __restrict__ o, int n){
  int i = blockIdx.x * 256 + threadIdx.x;
  if (i < n){
    unsigned k = o[i];
    o[i] = (k & 0x80000000u) ? (k & 0x7FFFFFFFu) : ~k;
  }
}

extern "C" void kernel_launch(void* const* d_in, const int* in_sizes, int n_in,
                              void* d_out, int out_size, void* d_ws, size_t ws_size,
                              hipStream_t stream){
  const float* x   = (const float*)d_in[0];
  const float* emb = (const float*)d_in[1];
  const int*   lab = (const int*)d_in[2];
  const int B = in_sizes[0] / D_;        // 256
  const int N = in_sizes[1] / D_;        // 200000
  const int C = out_size / B;            // 1000

  const int PNfull = (N + 63) / 64;      // 3125
  const int XB = (B + 63) / 64;          // 4
  const int HB = 208;

  char* ws = (char*)d_ws;
  size_t off = 0;
  unsigned short* xn = (unsigned short*)(ws); off += ((size_t)B * D_ * 2 + 255) & ~(size_t)255;
  unsigned* hist   = (unsigned*)(ws + off); off += 4096;
  unsigned* cursor = (unsigned*)(ws + off); off += 4096;
  unsigned* cbase  = (unsigned*)(ws + off); off += 4096;
  size_t narr = ((size_t)N * 4 + 255) & ~(size_t)255;
  int* perm   = (int*)(ws + off); off += narr;
  int* slab   = (int*)(ws + off); off += narr;
  unsigned short* nrmlin = (unsigned short*)(ws + off);
  size_t need = off + (size_t)N * D_ * 2;
  const bool fast = (ws_size >= need);
  const int PN = fast ? PNfull : 0;      // skip nrm role if ws too small

  hipMemsetAsync(hist, 0, 4096, stream);
  k_prep<<<PN + XB + HB, 256, 0, stream>>>(emb, x, nrmlin, xn, lab, hist,
                                           N, B, C, PN, XB, HB);
  k_scan<<<1, 1024, 0, stream>>>(hist, cursor, cbase, C);
  k_scatter<<<208, 256, 0, stream>>>(lab, cursor, perm, slab, N);
  if (fast){
    k_gemm_cls<<<C, 256, 0, stream>>>(nrmlin, xn, perm, cbase, hist,
                                      (float*)d_out, N, C);
  } else {
    const int IB = (B * C + 255) / 256;
    k_init_out<<<IB, 256, 0, stream>>>((unsigned*)d_out, B * C);
    k_gemm_gather<<<PNfull, 256, 0, stream>>>(emb, xn, perm, slab, (unsigned*)d_out, N, C);
    k_finalize<<<IB, 256, 0, stream>>>((unsigned*)d_out, B * C);
  }
}